// Round 10
// baseline (295.587 us; speedup 1.0000x reference)
//
#include <hip/hip_runtime.h>
#include <math.h>

#define NB 4
#define SEQ 4096
#define DM 1024
#define NG 4
#define DI 512
#define NQS 1024
#define NKS 512
#define NHD 8
#define DHD 64
#define VTS 520  // vtbuf row stride (512 cols used, padded)

typedef unsigned int u32;
typedef unsigned short u16;
typedef __bf16 bf16x8 __attribute__((ext_vector_type(8)));
typedef float f32x4 __attribute__((ext_vector_type(4)));

__device__ __forceinline__ float bf2f(u16 u) { return __uint_as_float(((u32)u) << 16); }
__device__ __forceinline__ u16 f2bf(float f) {
  u32 u = __float_as_uint(f);
  u32 r = (u + 0x7FFFu + ((u >> 16) & 1u)) >> 16;
  return (u16)r;
}
// hardware RNE bf16 convert (compiler pairs into v_cvt_pk_bf16_f32)
__device__ __forceinline__ u16 f2bfh(float f) {
  union { __bf16 b; u16 u; } cv;
  cv.b = (__bf16)f;
  return cv.u;
}

// ---------------- router: logits + xbf emit, 2 tokens per wave ----------------
__global__ __launch_bounds__(256) void router_kernel(
    const float* __restrict__ x, const float* __restrict__ wqr,
    const float* __restrict__ wkvr, float* __restrict__ qlog,
    float* __restrict__ kvlog, u16* __restrict__ xbf) {
  int tid = threadIdx.x;
  int base = blockIdx.x * 8 + (tid >> 6) * 2;  // 2 consecutive tokens per wave
  int lane = tid & 63;
  int b = base >> 12, tok = base & 4095;
  const float4* xr0 = (const float4*)(x + ((size_t)(b * SEQ + tok)) * DM);
  const float4* xr1 = xr0 + 256;  // next token row (1024 floats)
  float4 xv0[4], xv1[4];
#pragma unroll
  for (int i = 0; i < 4; i++) {
    xv0[i] = xr0[i * 64 + lane];
    xv1[i] = xr1[i * 64 + lane];
  }
  // emit bf16 rows (coalesced)
  ushort4* xrow0 = (ushort4*)(xbf + ((size_t)(b * SEQ + tok)) * DM);
  ushort4* xrow1 = xrow0 + 256;
#pragma unroll
  for (int i = 0; i < 4; i++) {
    ushort4 o0, o1;
    o0.x = f2bf(xv0[i].x); o0.y = f2bf(xv0[i].y);
    o0.z = f2bf(xv0[i].z); o0.w = f2bf(xv0[i].w);
    o1.x = f2bf(xv1[i].x); o1.y = f2bf(xv1[i].y);
    o1.z = f2bf(xv1[i].z); o1.w = f2bf(xv1[i].w);
    xrow0[i * 64 + lane] = o0;
    xrow1[i * 64 + lane] = o1;
  }
  float a0[8], a1[8];
#pragma unroll
  for (int r = 0; r < 8; r++) {
    const float4* wr =
        (const float4*)(r < 4 ? wqr + (r << 10) : wkvr + ((r - 4) << 10));
    float s0 = 0.f, s1 = 0.f;
#pragma unroll
    for (int i = 0; i < 4; i++) {
      float4 w4 = wr[i * 64 + lane];  // loaded once, used for both tokens
      s0 += xv0[i].x * w4.x + xv0[i].y * w4.y + xv0[i].z * w4.z + xv0[i].w * w4.w;
      s1 += xv1[i].x * w4.x + xv1[i].y * w4.y + xv1[i].z * w4.z + xv1[i].w * w4.w;
    }
    a0[r] = s0; a1[r] = s1;
  }
#pragma unroll
  for (int r = 0; r < 8; r++) {
#pragma unroll
    for (int off = 32; off >= 1; off >>= 1) {
      a0[r] += __shfl_xor(a0[r], off);
      a1[r] += __shfl_xor(a1[r], off);
    }
    if (lane == 0) {
      if (r < 4) {
        qlog[((b << 2) | r) * SEQ + tok] = a0[r];
        qlog[((b << 2) | r) * SEQ + tok + 1] = a1[r];
      } else {
        kvlog[((b << 2) | (r - 4)) * SEQ + tok] = a0[r];
        kvlog[((b << 2) | (r - 4)) * SEQ + tok + 1] = a1[r];
      }
    }
  }
}

// ---------------- merged top-k + qpos build + weight conversion ----------------
// blocks 0-15: q top-k (K=1024) + qpos; blocks 16-31: kv top-k (K=512);
// blocks 32..2079: fp32->bf16 weight conversion (hidden under topk latency).
// Radix select on the top 20 bits, 2 bits per pass (10 passes). Boundary
// bucket resolved exactly via eqlist ranked by (full key desc, index asc).
__global__ __launch_bounds__(256) void topk_kernel(
    const float* __restrict__ qlog, const float* __restrict__ kvlog,
    int* __restrict__ qidx, float* __restrict__ qscore,
    int* __restrict__ kvidx, float* __restrict__ kvscore,
    int* __restrict__ qpos, const float* __restrict__ wq,
    const float* __restrict__ wkv, const float* __restrict__ wout,
    u16* __restrict__ wqbf, u16* __restrict__ wkvbf, u16* __restrict__ woutbf) {
  int tid = threadIdx.x;
  if (blockIdx.x >= 32) {
    // weight conversion: 2,097,152 float4 over 2048 blocks = 1024/block
    int cid = blockIdx.x - 32;
#pragma unroll
    for (int j = 0; j < 4; j++) {
      int idx = cid * 1024 + j * 256 + tid;
      const float* src; u16* dst; int off;
      if (idx < 524288)        { src = wq;   dst = wqbf;   off = idx; }
      else if (idx < 1572864)  { src = wkv;  dst = wkvbf;  off = idx - 524288; }
      else                     { src = wout; dst = woutbf; off = idx - 1572864; }
      float4 v = ((const float4*)src)[off];
      ushort4 o;
      o.x = f2bf(v.x); o.y = f2bf(v.y); o.z = f2bf(v.z); o.w = f2bf(v.w);
      ((ushort4*)dst)[off] = o;
    }
    return;
  }
  __shared__ u32 keys[4096];
  __shared__ int eqlist[2048];
  __shared__ int scnt[12];
  __shared__ int s_gt, s_eq;
  int which = blockIdx.x >> 4;
  int bg = blockIdx.x & 15;
  int K = (which == 0) ? NQS : NKS;
  const float* L = ((which == 0) ? qlog : kvlog) + bg * 4096;
  int* out_idx = ((which == 0) ? qidx : kvidx) + bg * K;
  float* out_score = ((which == 0) ? qscore : kvscore) + bg * K;
  int* qposb = qpos + bg * 4096;
  // load keys; same-thread partition then overwrites the region with -1
  for (int e = tid; e < 4096; e += 256) {
    u32 u = __float_as_uint(L[e]);
    keys[e] = (u >> 31) ? ~u : (u | 0x80000000u);
  }
  if (which == 0)
    for (int e = tid; e < 4096; e += 256) qposb[e] = -1;
  if (tid == 0) { s_gt = 0; s_eq = 0; }
  __syncthreads();
  u32 prefix = 0;
  int remaining = K;
  for (int bit = 30; bit >= 12; bit -= 2) {  // bit pairs (31,30)..(13,12)
    u32 maskhi = (bit >= 30) ? 0u : (0xFFFFFFFFu << (bit + 2));
    int c3 = 0, c2 = 0, c1 = 0;
    for (int e = tid; e < 4096; e += 256) {
      u32 k = keys[e];
      if ((k & maskhi) == prefix) {
        u32 bkt = (k >> bit) & 3u;
        c3 += (bkt == 3u); c2 += (bkt == 2u); c1 += (bkt == 1u);
      }
    }
#pragma unroll
    for (int off = 32; off >= 1; off >>= 1) {
      c3 += __shfl_xor(c3, off);
      c2 += __shfl_xor(c2, off);
      c1 += __shfl_xor(c1, off);
    }
    if ((tid & 63) == 0) {
      int wv = tid >> 6;
      scnt[wv * 3 + 0] = c3; scnt[wv * 3 + 1] = c2; scnt[wv * 3 + 2] = c1;
    }
    __syncthreads();
    int n3 = scnt[0] + scnt[3] + scnt[6] + scnt[9];
    int n2 = scnt[1] + scnt[4] + scnt[7] + scnt[10];
    int n1 = scnt[2] + scnt[5] + scnt[8] + scnt[11];
    if (n3 >= remaining) prefix |= 3u << bit;
    else if (n3 + n2 >= remaining) { prefix |= 2u << bit; remaining -= n3; }
    else if (n3 + n2 + n1 >= remaining) { prefix |= 1u << bit; remaining -= n3 + n2; }
    else remaining -= (n3 + n2 + n1);
    __syncthreads();
  }
  u32 T = prefix;  // bits 31..12; bits 11..0 are zero
  for (int e = tid; e < 4096; e += 256) {
    u32 k = keys[e];
    u32 k20 = k & 0xFFFFF000u;
    if (k20 > T) {
      int pos = atomicAdd(&s_gt, 1);
      out_idx[pos] = e;
      u32 uo = (k >> 31) ? (k & 0x7FFFFFFFu) : ~k;  // invert radix key -> bits of L[e]
      float v = __uint_as_float(uo);
      out_score[pos] = 1.0f / (1.0f + __expf(-v));
      if (which == 0) qposb[e] = pos;
    } else if (k20 == T) {
      int p = atomicAdd(&s_eq, 1);
      if (p < 2048) eqlist[p] = e;
    }
  }
  __syncthreads();
  int gt = s_gt;
  int eq = min(s_eq, 2048);
  int need = K - gt;
  for (int i = tid; i < eq; i += 256) {
    int my = eqlist[i];
    u32 myk = keys[my];
    int rank = 0;
    for (int j = 0; j < eq; j++) {
      u32 kj = keys[eqlist[j]];
      rank += (kj > myk || (kj == myk && eqlist[j] < my)) ? 1 : 0;
    }
    if (rank < need) {
      int pos = gt + rank;
      out_idx[pos] = my;
      u32 uo = (myk >> 31) ? (myk & 0x7FFFFFFFu) : ~myk;
      float v = __uint_as_float(uo);
      out_score[pos] = 1.0f / (1.0f + __expf(-v));
      if (which == 0) qposb[my] = pos;
    }
  }
}

// ---------------- shared MFMA GEMM core: 128x128 tile, BK=64, swizzled LDS ----------------
// 512 threads (8 waves, 2x4 wave grid, per-wave output 64x32): same tile and
// dbuf issue-early schedule as before, but 2x the waves/CU in steady state
// (LDS caps at 2 blocks/CU -> 16 waves/CU) so co-resident blocks' MFMA hides
// the other block's barrier vmcnt drain (m114 co-scheduling).
struct Ptr2 { const u16* a[2]; const u16* b[2]; };

__device__ __forceinline__ void stage_tile512(const Ptr2& P, u16* Asmb,
                                              u16* Bsmb, int kt, int w) {
#pragma unroll
  for (int r = 0; r < 2; r++) {
    char* ldsA = (char*)Asmb + (r * 512 + w * 64) * 16;
    __builtin_amdgcn_global_load_lds(
        (const __attribute__((address_space(1))) void*)(P.a[r] + kt * 64),
        (__attribute__((address_space(3))) void*)ldsA, 16, 0, 0);
    char* ldsB = (char*)Bsmb + (r * 512 + w * 64) * 16;
    __builtin_amdgcn_global_load_lds(
        (const __attribute__((address_space(1))) void*)(P.b[r] + kt * 64),
        (__attribute__((address_space(3))) void*)ldsB, 16, 0, 0);
  }
}

__device__ __forceinline__ void mfma_core512(Ptr2 P, u16* Asm0, u16* Bsm0,
                                             u16* Asm1, u16* Bsm1, int ktiles,
                                             int tid, f32x4 (&acc)[4][2]) {
  int w = tid >> 6, lane = tid & 63;
  int col = lane & 15, quad = lane >> 4;
  int wr = w >> 2, wc = w & 3;
  stage_tile512(P, Asm0, Bsm0, 0, w);
  __syncthreads();
  for (int kt = 0; kt < ktiles; kt++) {
    const u16* Ac = (kt & 1) ? Asm1 : Asm0;
    const u16* Bc = (kt & 1) ? Bsm1 : Bsm0;
    if (kt + 1 < ktiles)
      stage_tile512(P, (kt & 1) ? Asm0 : Asm1, (kt & 1) ? Bsm0 : Bsm1, kt + 1, w);
#pragma unroll
    for (int k04 = 0; k04 < 8; k04 += 4) {
      bf16x8 af[4], bfr[2];
#pragma unroll
      for (int t = 0; t < 4; t++) {
        int rowa = wr * 64 + t * 16 + col;
        int sp = (quad + k04) ^ (col & 7);
        af[t] = *(const bf16x8*)((const char*)Ac + (rowa * 8 + sp) * 16);
      }
#pragma unroll
      for (int u = 0; u < 2; u++) {
        int rowb = wc * 32 + u * 16 + col;
        int sp = (quad + k04) ^ (col & 7);
        bfr[u] = *(const bf16x8*)((const char*)Bc + (rowb * 8 + sp) * 16);
      }
#pragma unroll
      for (int t = 0; t < 4; t++)
#pragma unroll
        for (int u = 0; u < 2; u++)
          acc[t][u] = __builtin_amdgcn_mfma_f32_16x16x32_bf16(af[t], bfr[u], acc[t][u], 0, 0, 0);
    }
    __syncthreads();
  }
}

// ---------------- fused q+kv projection (even/odd interleave, 512 threads) ----------------
__global__ __launch_bounds__(512) void gemm_qkvproj(
    const u16* __restrict__ xbf, const int* __restrict__ qidx,
    const int* __restrict__ kvidx, const u16* __restrict__ wqbf,
    const u16* __restrict__ wkvbf, const float* __restrict__ kvscore,
    u16* __restrict__ qbuf, u16* __restrict__ kbuf, u16* __restrict__ vtbuf) {
  __shared__ __align__(16) u16 Asm[2][8192], Bsm[2][8192];
  __shared__ int ridx[128];
  int tid = threadIdx.x;
  int id = blockIdx.x;
  bool is_q = (id & 1) == 0;
  int sid = id >> 1;                 // 0..511 either way
  int bg = sid >> 5, r5 = sid & 31;
  int b = bg >> 2, g = bg & 3;
  int w = tid >> 6, lane = tid & 63;
  int col = lane & 15, quad = lane >> 4;
  int wr = w >> 2, wc = w & 3;

  if (is_q) {
    int col0 = (r5 & 3) * 128, row0 = (r5 >> 2) * 128;
    if (tid < 128) ridx[tid] = qidx[bg * NQS + row0 + tid];
    __syncthreads();
    Ptr2 P;
#pragma unroll
    for (int r = 0; r < 2; r++) {
      int G = r * 512 + tid;
      int row = G >> 3;
      int seg = (G & 7) ^ (row & 7);
      P.a[r] = xbf + ((size_t)b * SEQ + ridx[row]) * DM + seg * 8;
      P.b[r] = wqbf + ((size_t)g * DI + col0 + row) * DM + seg * 8;
    }
    f32x4 acc[4][2] = {};
    mfma_core512(P, Asm[0], Bsm[0], Asm[1], Bsm[1], DM / 64, tid, acc);
#pragma unroll
    for (int t = 0; t < 4; t++)
#pragma unroll
      for (int u = 0; u < 2; u++)
#pragma unroll
        for (int r = 0; r < 4; r++) {
          int rowg = row0 + wr * 64 + t * 16 + quad * 4 + r;
          int colg = col0 + wc * 32 + u * 16 + col;
          // pre-scale q by DH^-0.5 = 0.125 (power of two: exact in bf16)
          qbuf[((size_t)bg * NQS + rowg) * DI + colg] = f2bf(acc[t][u][r] * 0.125f);
        }
  } else {
    int col0 = (r5 & 7) * 128, row0 = (r5 >> 3) * 128;
    if (tid < 128) ridx[tid] = kvidx[bg * NKS + row0 + tid];
    __syncthreads();
    Ptr2 P;
#pragma unroll
    for (int r = 0; r < 2; r++) {
      int G = r * 512 + tid;
      int row = G >> 3;
      int seg = (G & 7) ^ (row & 7);
      P.a[r] = xbf + ((size_t)b * SEQ + ridx[row]) * DM + seg * 8;
      P.b[r] = wkvbf + ((size_t)g * (2 * DI) + col0 + row) * DM + seg * 8;
    }
    f32x4 acc[4][2] = {};
    mfma_core512(P, Asm[0], Bsm[0], Asm[1], Bsm[1], DM / 64, tid, acc);
    if (col0 < DI) {
#pragma unroll
      for (int t = 0; t < 4; t++)
#pragma unroll
        for (int u = 0; u < 2; u++)
#pragma unroll
          for (int r = 0; r < 4; r++) {
            int rowg = row0 + wr * 64 + t * 16 + quad * 4 + r;
            int colg = col0 + wc * 32 + u * 16 + col;
            kbuf[((size_t)bg * NKS + rowg) * DI + colg] = f2bf(acc[t][u][r]);
          }
    } else {
#pragma unroll
      for (int t = 0; t < 4; t++) {
        int base = row0 + wr * 64 + t * 16 + quad * 4;  // base%4==0
        float sc0 = kvscore[bg * NKS + base + 0];
        float sc1 = kvscore[bg * NKS + base + 1];
        float sc2 = kvscore[bg * NKS + base + 2];
        float sc3 = kvscore[bg * NKS + base + 3];
#pragma unroll
        for (int u = 0; u < 2; u++) {
          int vc = col0 - DI + wc * 32 + u * 16 + col;  // 0..511
          int h = vc >> 6, d = vc & 63;
          u32 lo = (u32)f2bf(acc[t][u][0] * sc0) | ((u32)f2bf(acc[t][u][1] * sc1) << 16);
          u32 hi = (u32)f2bf(acc[t][u][2] * sc2) | ((u32)f2bf(acc[t][u][3] * sc3) << 16);
          // 4 consecutive n at one (h,d) row -> one aligned 8B store
          *(uint2*)&vtbuf[(((size_t)bg * NHD + h) * DHD + d) * VTS + base] =
              make_uint2(lo, hi);
        }
      }
    }
  }
}

// ---------------- out projection: bf16 oproj, 512 threads ----------------
__global__ __launch_bounds__(512) void gemm_outproj(
    const u16* __restrict__ obuf, const u16* __restrict__ woutbf,
    const float* __restrict__ qscore, u16* __restrict__ oproj_lo,
    u16* __restrict__ oproj_hi) {
  int bg = blockIdx.z, g = bg & 3;
  int row0 = blockIdx.y * 128, col0 = blockIdx.x * 128;
  __shared__ __align__(16) u16 Asm[2][8192], Bsm[2][8192];
  int tid = threadIdx.x;
  Ptr2 P;
#pragma unroll
  for (int r = 0; r < 2; r++) {
    int G = r * 512 + tid;
    int row = G >> 3;
    int seg = (G & 7) ^ (row & 7);
    P.a[r] = obuf + ((size_t)bg * NQS + row0 + row) * DI + seg * 8;
    P.b[r] = woutbf + ((size_t)g * DM + col0 + row) * DI + seg * 8;
  }
  f32x4 acc[4][2] = {};
  mfma_core512(P, Asm[0], Bsm[0], Asm[1], Bsm[1], DI / 64, tid, acc);
  int w = tid >> 6, lane = tid & 63;
  int col = lane & 15, quad = lane >> 4;
  int wr = w >> 2, wc = w & 3;
  u16* obase = (bg < 8 ? oproj_lo : oproj_hi) + (size_t)(bg & 7) * NQS * DM;
#pragma unroll
  for (int t = 0; t < 4; t++)
#pragma unroll
    for (int r = 0; r < 4; r++) {
      int rowg = row0 + wr * 64 + t * 16 + quad * 4 + r;
      float sc = qscore[bg * NQS + rowg];
      u16* orow = obase + (size_t)rowg * DM;
#pragma unroll
      for (int u = 0; u < 2; u++) {
        int colg = col0 + wc * 32 + u * 16 + col;
        orow[colg] = f2bfh(acc[t][u][r] * sc);
      }
    }
}

// ---------------- finalize: gather <=4 bf16 group rows, mean, null-token fill ----------------
__global__ __launch_bounds__(256) void finalize_gather(
    const u16* __restrict__ oproj_lo, const u16* __restrict__ oproj_hi,
    const int* __restrict__ qpos, const float* __restrict__ null_token,
    float* __restrict__ dout) {
  int blk = blockIdx.x;            // 0..16383 (4 b-values x 4096 tokens)
  int b = blk >> 12;
  int tok = blk & 4095;
  int tid = threadIdx.x;
  const u16* obase = (b < 2) ? oproj_lo : oproj_hi;
  int zoff = (b & 1) * 4;
  float4 acc = {0.f, 0.f, 0.f, 0.f};
  int cnt = 0;
#pragma unroll
  for (int g = 0; g < 4; g++) {
    int pos = qpos[(((b << 2) | g)) * 4096 + tok];  // block-uniform
    if (pos >= 0) {
      const uint2* row =
          (const uint2*)(obase + ((size_t)(zoff + g) * NQS + pos) * DM);
      uint2 v = row[tid];   // 4 bf16
      acc.x += bf2f((u16)(v.x & 0xFFFF));
      acc.y += bf2f((u16)(v.x >> 16));
      acc.z += bf2f((u16)(v.y & 0xFFFF));
      acc.w += bf2f((u16)(v.y >> 16));
      cnt++;
    }
  }
  float4* dst = (float4*)(dout + ((size_t)b * SEQ + tok) * DM) + tid;
  if (cnt > 0) {
    float inv = 1.0f / cnt;
    acc.x *= inv; acc.y *= inv; acc.z *= inv; acc.w *= inv;
    *dst = acc;
  } else {
    *dst = ((const float4*)null_token)[tid];
  }
}

// ---------------- MFMA flash attention v4 + XCD-local grid ----------------
__global__ __launch_bounds__(256, 4) void attn_mfma(
    const u16* __restrict__ qbuf, const u16* __restrict__ kbuf,
    const u16* __restrict__ vtbuf, const float* __restrict__ null_kv,
    u16* __restrict__ obuf) {
  int id = blockIdx.x;
  int qt = id >> 7;           // 0..7
  int h = id & 7;             // XCD selector (i%8 == h)
  int bg = (id >> 3) & 15;    // 0..15
  int g = bg & 3;
  int tid = threadIdx.x;
  int w = tid >> 6, lane = tid & 63;
  int col = lane & 15, quad = lane >> 4;

  __shared__ __align__(16) u16 Ks[64][72];
  __shared__ __align__(16) u16 Vts[64][72];
  __shared__ __align__(16) u16 Ps[4][32][72];

  int q0 = qt * 128 + w * 32;
  const u16* qp0 = qbuf + ((size_t)bg * NQS + q0 + col) * DI + h * DHD + quad * 8;
  bf16x8 qa[2][2];
  qa[0][0] = *(const bf16x8*)qp0;
  qa[0][1] = *(const bf16x8*)(qp0 + 32);
  qa[1][0] = *(const bf16x8*)(qp0 + 16 * DI);
  qa[1][1] = *(const bf16x8*)(qp0 + 16 * DI + 32);

  // --- null-column prologue: exact online-softmax init (per-lane q = col) ---
  const float* kn = null_kv + ((size_t)(0 * NG + g) * NHD + h) * DHD;
  const float* vn = null_kv + ((size_t)(1 * NG + g) * NHD + h) * DHD;
  float m_run[2], l_lane[2];
  f32x4 oacc[2][4];
#pragma unroll
  for (int s = 0; s < 2; s++) {
    float sn = 0.f;
#pragma unroll
    for (int i = 0; i < 8; i++) {
      sn += (float)qa[s][0][i] * kn[quad * 8 + i];
      sn += (float)qa[s][1][i] * kn[32 + quad * 8 + i];
    }
    sn += __shfl_xor(sn, 16);
    sn += __shfl_xor(sn, 32);
    m_run[s] = sn;                       // running max = s_null, p_null = 1
    l_lane[s] = (quad == 0) ? 1.f : 0.f; // null's contribution, seeded once
  }
#pragma unroll
  for (int t = 0; t < 4; t++) {
    float v = vn[t * 16 + col];          // oacc0 = 1 * v_null (all q rows)
    f32x4 tmp = {v, v, v, v};
    oacc[0][t] = tmp;
    oacc[1][t] = tmp;
  }

  // --- staging: 64x64 K tile + 64x64 V^T tile, 32B per thread each ---
  int sr = tid >> 2, ss = tid & 3;
  const u16* kptr = kbuf + ((size_t)bg * NKS + sr) * DI + h * DHD + ss * 16;
  const u16* vptr = vtbuf + (((size_t)bg * NHD + h) * DHD + sr) * VTS + ss * 16;
  uint4* kdst = (uint4*)&Ks[sr][ss * 16];
  uint4* vdst = (uint4*)&Vts[sr][ss * 16];
  uint4 ck0, ck1, cv0, cv1;
  { const uint4* p = (const uint4*)kptr; ck0 = p[0]; ck1 = p[1]; }
  { const uint4* p = (const uint4*)vptr; cv0 = p[0]; cv1 = p[1]; }

  for (int c = 0; c < 8; ++c) {
    // write-late: regs (loaded last iteration) -> LDS; then issue-early next
    kdst[0] = ck0; kdst[1] = ck1;
    vdst[0] = cv0; vdst[1] = cv1;
    if (c < 7) {
      const uint4* p = (const uint4*)(kptr + (size_t)(c + 1) * 64 * DI);
      ck0 = p[0]; ck1 = p[1];
      const uint4* q4 = (const uint4*)(vptr + (c + 1) * 64);
      cv0 = q4[0]; cv1 = q4[1];
    }
    __syncthreads();

    // QK^T swapped: sv[s][t] rows = k (quad*4+r within 16-tile t), col = q
    f32x4 sv[2][4];
#pragma unroll
    for (int t = 0; t < 4; t++) {
      bf16x8 kb0 = *(const bf16x8*)&Ks[t * 16 + col][quad * 8];
      bf16x8 kb1 = *(const bf16x8*)&Ks[t * 16 + col][quad * 8 + 32];
      f32x4 z = {0.f, 0.f, 0.f, 0.f};
      f32x4 s0 = __builtin_amdgcn_mfma_f32_16x16x32_bf16(kb0, qa[0][0], z, 0, 0, 0);
      sv[0][t] = __builtin_amdgcn_mfma_f32_16x16x32_bf16(kb1, qa[0][1], s0, 0, 0, 0);
      f32x4 s1 = __builtin_amdgcn_mfma_f32_16x16x32_bf16(kb0, qa[1][0], z, 0, 0, 0);
      sv[1][t] = __builtin_amdgcn_mfma_f32_16x16x32_bf16(kb1, qa[1][1], s1, 0, 0, 0);
    }

    // softmax per q-subtile (per-lane: one q = col, 16 k-values in-register)
#pragma unroll
    for (int s = 0; s < 2; s++) {
      float pm = sv[s][0][0];
#pragma unroll
      for (int t = 0; t < 4; t++)
#pragma unroll
        for (int r = 0; r < 4; r++) pm = fmaxf(pm, sv[s][t][r]);
      pm = fmaxf(pm, __shfl_xor(pm, 16));
      pm = fmaxf(pm, __shfl_xor(pm, 32));
      if (!__all(pm <= m_run[s] + 8.0f)) {   // T13 defer-max
        float mnew = fmaxf(m_run[s], pm);
        float alpha = __expf(m_run[s] - mnew);
        m_run[s] = mnew;
        l_lane[s] *= alpha;
#pragma unroll
        for (int r = 0; r < 4; r++) {
          float a_o = __shfl(alpha, quad * 4 + r);
#pragma unroll
          for (int t = 0; t < 4; t++) oacc[s][t][r] *= a_o;
        }
      }
      float rs = 0.f;
#pragma unroll
      for (int t = 0; t < 4; t++) {
        float p0 = __expf(sv[s][t][0] - m_run[s]);
        float p1 = __expf(sv[s][t][1] - m_run[s]);
        float p2 = __expf(sv[s][t][2] - m_run[s]);
        float p3 = __expf(sv[s][t][3] - m_run[s]);
        rs += (p0 + p1) + (p2 + p3);
        u32 lo = (u32)f2bfh(p0) | ((u32)f2bfh(p1) << 16);
        u32 hi = (u32)f2bfh(p2) | ((u32)f2bfh(p3) << 16);
        // 4 consecutive k per lane -> one b64 store
        *(uint2*)&Ps[w][s * 16 + col][t * 16 + quad * 4] = make_uint2(lo, hi);
      }
      l_lane[s] += rs;
    }

    // PV: vb fragments reused for both q-subtiles
#pragma unroll
    for (int s2 = 0; s2 < 2; s2++) {
      bf16x8 pa0 = *(const bf16x8*)&Ps[w][col][s2 * 32 + quad * 8];
      bf16x8 pa1 = *(const bf16x8*)&Ps[w][16 + col][s2 * 32 + quad * 8];
#pragma unroll
      for (int t = 0; t < 4; t++) {
        bf16x8 vb = *(const bf16x8*)&Vts[t * 16 + col][s2 * 32 + quad * 8];
        oacc[0][t] = __builtin_amdgcn_mfma_f32_16x16x32_bf16(pa0, vb, oacc[0][t], 0, 0, 0);
        oacc[1][t] = __builtin_amdgcn_mfma_f32_16x16x32_bf16(pa1, vb, oacc[1][t], 0, 0, 0);
      }
    }
    __syncthreads();
  }

  // epilogue: reduce l across quads, redistribute to C layout, write
#pragma unroll
  for (int s = 0; s < 2; s++) {
    float l = l_lane[s];
    l += __shfl_xor(l, 16);
    l += __shfl_xor(l, 32);
    float inv = 1.0f / l;
#pragma unroll
    for (int r = 0; r < 4; r++) {
      float ir = __shfl(inv, quad * 4 + r);
#pragma unroll
      for (int t = 0; t < 4; t++) {
        obuf[((size_t)bg * NQS + q0 + s * 16 + quad * 4 + r) * DI + h * DHD +
             t * 16 + col] = f2bfh(oacc[s][t][r] * ir);
      }
    }
  }
}

extern "C" void kernel_launch(void* const* d_in, const int* in_sizes, int n_in,
                              void* d_out, int out_size, void* d_ws, size_t ws_size,
                              hipStream_t stream) {
  const float* x = (const float*)d_in[0];
  const float* wqr = (const float*)d_in[1];
  const float* wkvr = (const float*)d_in[2];
  const float* wq = (const float*)d_in[3];
  const float* wkv = (const float*)d_in[4];
  const float* wout = (const float*)d_in[5];
  const float* nullkv = (const float*)d_in[6];
  const float* nulltok = (const float*)d_in[7];
  float* out = (float*)d_out;
  char* ws = (char*)d_ws;
  // workspace layout (bytes)
  float* qlog = (float*)(ws + 0);                  // 256 KB
  float* kvlog = (float*)(ws + 262144);            // 256 KB
  int* qidx = (int*)(ws + 524288);                 // 64 KB
  int* kvidx = (int*)(ws + 589824);                // 32 KB
  float* qscore = (float*)(ws + 622592);           // 64 KB
  float* kvscore = (float*)(ws + 688128);          // 32 KB
  u16* qbuf = (u16*)(ws + 786432);                 // 16 MB  [16][1024][512]
  u16* kbuf = (u16*)(ws + 17563648);               // 8 MB   [16][512][512]
  u16* vtbuf = (u16*)(ws + 25952256);              // 8.13MB [16][8][64][520]
  u16* obuf = (u16*)(ws + 34476032);               // 16 MB  [16][1024][512]
  u16* xbf = (u16*)(ws + 51253248);                // 32 MB  [4][4096][1024]
  u16* wqbf = (u16*)(ws + 84807680);               // 4 MB   [4][512][1024]
  u16* wkvbf = (u16*)(ws + 89001984);              // 8 MB   [4][1024][1024]
  u16* woutbf = (u16*)(ws + 97390592);             // 4 MB   [4][1024][512]
  // dead-region reuse (stream-ordered):
  //  - qpos (256 KB) in qlog's region, written directly by topk
  //  - oproj_lo (16 MB bf16, bg 0..7)  in qbuf region (dead after attn)
  //  - oproj_hi (16 MB bf16, bg 8..15) in xbf region (dead after qkvproj)
  int* qpos = (int*)(ws + 0);
  u16* oproj_lo = (u16*)(ws + 786432);
  u16* oproj_hi = (u16*)(ws + 51253248);

  router_kernel<<<2048, 256, 0, stream>>>(x, wqr, wkvr, qlog, kvlog, xbf);
  topk_kernel<<<2080, 256, 0, stream>>>(qlog, kvlog, qidx, qscore, kvidx,
                                        kvscore, qpos, wq, wkv, wout, wqbf,
                                        wkvbf, woutbf);
  gemm_qkvproj<<<1024, 512, 0, stream>>>(xbf, qidx, kvidx, wqbf, wkvbf, kvscore,
                                         qbuf, kbuf, vtbuf);
  attn_mfma<<<1024, 256, 0, stream>>>(qbuf, kbuf, vtbuf, nullkv, obuf);
  gemm_outproj<<<dim3(8, 8, 16), 512, 0, stream>>>(obuf, woutbf, qscore,
                                                   oproj_lo, oproj_hi);
  finalize_gather<<<16384, 256, 0, stream>>>(oproj_lo, oproj_hi, qpos, nulltok,
                                             out);
}

// Round 11
// 289.255 us; speedup vs baseline: 1.0219x; 1.0219x over previous
//
#include <hip/hip_runtime.h>
#include <math.h>

#define NB 4
#define SEQ 4096
#define DM 1024
#define NG 4
#define DI 512
#define NQS 1024
#define NKS 512
#define NHD 8
#define DHD 64
#define VTS 520  // vtbuf row stride (512 cols used, padded)

typedef unsigned int u32;
typedef unsigned short u16;
typedef __bf16 bf16x8 __attribute__((ext_vector_type(8)));
typedef float f32x4 __attribute__((ext_vector_type(4)));

__device__ __forceinline__ float bf2f(u16 u) { return __uint_as_float(((u32)u) << 16); }
__device__ __forceinline__ u16 f2bf(float f) {
  u32 u = __float_as_uint(f);
  u32 r = (u + 0x7FFFu + ((u >> 16) & 1u)) >> 16;
  return (u16)r;
}
// hardware RNE bf16 convert (compiler pairs into v_cvt_pk_bf16_f32)
__device__ __forceinline__ u16 f2bfh(float f) {
  union { __bf16 b; u16 u; } cv;
  cv.b = (__bf16)f;
  return cv.u;
}

// ---------------- router: logits + xbf emit, 2 tokens per wave ----------------
__global__ __launch_bounds__(256) void router_kernel(
    const float* __restrict__ x, const float* __restrict__ wqr,
    const float* __restrict__ wkvr, float* __restrict__ qlog,
    float* __restrict__ kvlog, u16* __restrict__ xbf) {
  int tid = threadIdx.x;
  int base = blockIdx.x * 8 + (tid >> 6) * 2;  // 2 consecutive tokens per wave
  int lane = tid & 63;
  int b = base >> 12, tok = base & 4095;
  const float4* xr0 = (const float4*)(x + ((size_t)(b * SEQ + tok)) * DM);
  const float4* xr1 = xr0 + 256;  // next token row (1024 floats)
  float4 xv0[4], xv1[4];
#pragma unroll
  for (int i = 0; i < 4; i++) {
    xv0[i] = xr0[i * 64 + lane];
    xv1[i] = xr1[i * 64 + lane];
  }
  // emit bf16 rows (coalesced)
  ushort4* xrow0 = (ushort4*)(xbf + ((size_t)(b * SEQ + tok)) * DM);
  ushort4* xrow1 = xrow0 + 256;
#pragma unroll
  for (int i = 0; i < 4; i++) {
    ushort4 o0, o1;
    o0.x = f2bf(xv0[i].x); o0.y = f2bf(xv0[i].y);
    o0.z = f2bf(xv0[i].z); o0.w = f2bf(xv0[i].w);
    o1.x = f2bf(xv1[i].x); o1.y = f2bf(xv1[i].y);
    o1.z = f2bf(xv1[i].z); o1.w = f2bf(xv1[i].w);
    xrow0[i * 64 + lane] = o0;
    xrow1[i * 64 + lane] = o1;
  }
  float a0[8], a1[8];
#pragma unroll
  for (int r = 0; r < 8; r++) {
    const float4* wr =
        (const float4*)(r < 4 ? wqr + (r << 10) : wkvr + ((r - 4) << 10));
    float s0 = 0.f, s1 = 0.f;
#pragma unroll
    for (int i = 0; i < 4; i++) {
      float4 w4 = wr[i * 64 + lane];  // loaded once, used for both tokens
      s0 += xv0[i].x * w4.x + xv0[i].y * w4.y + xv0[i].z * w4.z + xv0[i].w * w4.w;
      s1 += xv1[i].x * w4.x + xv1[i].y * w4.y + xv1[i].z * w4.z + xv1[i].w * w4.w;
    }
    a0[r] = s0; a1[r] = s1;
  }
#pragma unroll
  for (int r = 0; r < 8; r++) {
#pragma unroll
    for (int off = 32; off >= 1; off >>= 1) {
      a0[r] += __shfl_xor(a0[r], off);
      a1[r] += __shfl_xor(a1[r], off);
    }
    if (lane == 0) {
      if (r < 4) {
        qlog[((b << 2) | r) * SEQ + tok] = a0[r];
        qlog[((b << 2) | r) * SEQ + tok + 1] = a1[r];
      } else {
        kvlog[((b << 2) | (r - 4)) * SEQ + tok] = a0[r];
        kvlog[((b << 2) | (r - 4)) * SEQ + tok + 1] = a1[r];
      }
    }
  }
}

// ---------------- merged top-k + qpos build + weight conversion ----------------
// blocks 0-15: q top-k (K=1024) + qpos; blocks 16-31: kv top-k (K=512);
// blocks 32..2079: fp32->bf16 weight conversion (hidden under topk latency).
// Radix select on the top 20 bits, 2 bits per pass (10 passes). Boundary
// bucket resolved exactly via eqlist ranked by (full key desc, index asc).
__global__ __launch_bounds__(256) void topk_kernel(
    const float* __restrict__ qlog, const float* __restrict__ kvlog,
    int* __restrict__ qidx, float* __restrict__ qscore,
    int* __restrict__ kvidx, float* __restrict__ kvscore,
    int* __restrict__ qpos, const float* __restrict__ wq,
    const float* __restrict__ wkv, const float* __restrict__ wout,
    u16* __restrict__ wqbf, u16* __restrict__ wkvbf, u16* __restrict__ woutbf) {
  int tid = threadIdx.x;
  if (blockIdx.x >= 32) {
    // weight conversion: 2,097,152 float4 over 2048 blocks = 1024/block
    int cid = blockIdx.x - 32;
#pragma unroll
    for (int j = 0; j < 4; j++) {
      int idx = cid * 1024 + j * 256 + tid;
      const float* src; u16* dst; int off;
      if (idx < 524288)        { src = wq;   dst = wqbf;   off = idx; }
      else if (idx < 1572864)  { src = wkv;  dst = wkvbf;  off = idx - 524288; }
      else                     { src = wout; dst = woutbf; off = idx - 1572864; }
      float4 v = ((const float4*)src)[off];
      ushort4 o;
      o.x = f2bf(v.x); o.y = f2bf(v.y); o.z = f2bf(v.z); o.w = f2bf(v.w);
      ((ushort4*)dst)[off] = o;
    }
    return;
  }
  __shared__ u32 keys[4096];
  __shared__ int eqlist[2048];
  __shared__ int scnt[12];
  __shared__ int s_gt, s_eq;
  int which = blockIdx.x >> 4;
  int bg = blockIdx.x & 15;
  int K = (which == 0) ? NQS : NKS;
  const float* L = ((which == 0) ? qlog : kvlog) + bg * 4096;
  int* out_idx = ((which == 0) ? qidx : kvidx) + bg * K;
  float* out_score = ((which == 0) ? qscore : kvscore) + bg * K;
  int* qposb = qpos + bg * 4096;
  // load keys; same-thread partition then overwrites the region with -1
  for (int e = tid; e < 4096; e += 256) {
    u32 u = __float_as_uint(L[e]);
    keys[e] = (u >> 31) ? ~u : (u | 0x80000000u);
  }
  if (which == 0)
    for (int e = tid; e < 4096; e += 256) qposb[e] = -1;
  if (tid == 0) { s_gt = 0; s_eq = 0; }
  __syncthreads();
  u32 prefix = 0;
  int remaining = K;
  for (int bit = 30; bit >= 12; bit -= 2) {  // bit pairs (31,30)..(13,12)
    u32 maskhi = (bit >= 30) ? 0u : (0xFFFFFFFFu << (bit + 2));
    int c3 = 0, c2 = 0, c1 = 0;
    for (int e = tid; e < 4096; e += 256) {
      u32 k = keys[e];
      if ((k & maskhi) == prefix) {
        u32 bkt = (k >> bit) & 3u;
        c3 += (bkt == 3u); c2 += (bkt == 2u); c1 += (bkt == 1u);
      }
    }
#pragma unroll
    for (int off = 32; off >= 1; off >>= 1) {
      c3 += __shfl_xor(c3, off);
      c2 += __shfl_xor(c2, off);
      c1 += __shfl_xor(c1, off);
    }
    if ((tid & 63) == 0) {
      int wv = tid >> 6;
      scnt[wv * 3 + 0] = c3; scnt[wv * 3 + 1] = c2; scnt[wv * 3 + 2] = c1;
    }
    __syncthreads();
    int n3 = scnt[0] + scnt[3] + scnt[6] + scnt[9];
    int n2 = scnt[1] + scnt[4] + scnt[7] + scnt[10];
    int n1 = scnt[2] + scnt[5] + scnt[8] + scnt[11];
    if (n3 >= remaining) prefix |= 3u << bit;
    else if (n3 + n2 >= remaining) { prefix |= 2u << bit; remaining -= n3; }
    else if (n3 + n2 + n1 >= remaining) { prefix |= 1u << bit; remaining -= n3 + n2; }
    else remaining -= (n3 + n2 + n1);
    __syncthreads();
  }
  u32 T = prefix;  // bits 31..12; bits 11..0 are zero
  for (int e = tid; e < 4096; e += 256) {
    u32 k = keys[e];
    u32 k20 = k & 0xFFFFF000u;
    if (k20 > T) {
      int pos = atomicAdd(&s_gt, 1);
      out_idx[pos] = e;
      u32 uo = (k >> 31) ? (k & 0x7FFFFFFFu) : ~k;  // invert radix key -> bits of L[e]
      float v = __uint_as_float(uo);
      out_score[pos] = 1.0f / (1.0f + __expf(-v));
      if (which == 0) qposb[e] = pos;
    } else if (k20 == T) {
      int p = atomicAdd(&s_eq, 1);
      if (p < 2048) eqlist[p] = e;
    }
  }
  __syncthreads();
  int gt = s_gt;
  int eq = min(s_eq, 2048);
  int need = K - gt;
  for (int i = tid; i < eq; i += 256) {
    int my = eqlist[i];
    u32 myk = keys[my];
    int rank = 0;
    for (int j = 0; j < eq; j++) {
      u32 kj = keys[eqlist[j]];
      rank += (kj > myk || (kj == myk && eqlist[j] < my)) ? 1 : 0;
    }
    if (rank < need) {
      int pos = gt + rank;
      out_idx[pos] = my;
      u32 uo = (myk >> 31) ? (myk & 0x7FFFFFFFu) : ~myk;
      float v = __uint_as_float(uo);
      out_score[pos] = 1.0f / (1.0f + __expf(-v));
      if (which == 0) qposb[my] = pos;
    }
  }
}

// ---------------- shared MFMA GEMM core: 128x128 tile, BK=64, swizzled LDS ----------------
// 512 threads (8 waves, 2x4 wave grid, per-wave output 64x32), double-buffered
// issue-early schedule: 2 blocks/CU x 8 waves = 16 waves/CU steady state.
struct Ptr2 { const u16* a[2]; const u16* b[2]; };

__device__ __forceinline__ void stage_tile512(const Ptr2& P, u16* Asmb,
                                              u16* Bsmb, int kt, int w) {
#pragma unroll
  for (int r = 0; r < 2; r++) {
    char* ldsA = (char*)Asmb + (r * 512 + w * 64) * 16;
    __builtin_amdgcn_global_load_lds(
        (const __attribute__((address_space(1))) void*)(P.a[r] + kt * 64),
        (__attribute__((address_space(3))) void*)ldsA, 16, 0, 0);
    char* ldsB = (char*)Bsmb + (r * 512 + w * 64) * 16;
    __builtin_amdgcn_global_load_lds(
        (const __attribute__((address_space(1))) void*)(P.b[r] + kt * 64),
        (__attribute__((address_space(3))) void*)ldsB, 16, 0, 0);
  }
}

__device__ __forceinline__ void mfma_core512(Ptr2 P, u16* Asm0, u16* Bsm0,
                                             u16* Asm1, u16* Bsm1, int ktiles,
                                             int tid, f32x4 (&acc)[4][2]) {
  int w = tid >> 6, lane = tid & 63;
  int col = lane & 15, quad = lane >> 4;
  int wr = w >> 2, wc = w & 3;
  stage_tile512(P, Asm0, Bsm0, 0, w);
  __syncthreads();
  for (int kt = 0; kt < ktiles; kt++) {
    const u16* Ac = (kt & 1) ? Asm1 : Asm0;
    const u16* Bc = (kt & 1) ? Bsm1 : Bsm0;
    if (kt + 1 < ktiles)
      stage_tile512(P, (kt & 1) ? Asm0 : Asm1, (kt & 1) ? Bsm0 : Bsm1, kt + 1, w);
#pragma unroll
    for (int k04 = 0; k04 < 8; k04 += 4) {
      bf16x8 af[4], bfr[2];
#pragma unroll
      for (int t = 0; t < 4; t++) {
        int rowa = wr * 64 + t * 16 + col;
        int sp = (quad + k04) ^ (col & 7);
        af[t] = *(const bf16x8*)((const char*)Ac + (rowa * 8 + sp) * 16);
      }
#pragma unroll
      for (int u = 0; u < 2; u++) {
        int rowb = wc * 32 + u * 16 + col;
        int sp = (quad + k04) ^ (col & 7);
        bfr[u] = *(const bf16x8*)((const char*)Bc + (rowb * 8 + sp) * 16);
      }
#pragma unroll
      for (int t = 0; t < 4; t++)
#pragma unroll
        for (int u = 0; u < 2; u++)
          acc[t][u] = __builtin_amdgcn_mfma_f32_16x16x32_bf16(af[t], bfr[u], acc[t][u], 0, 0, 0);
    }
    __syncthreads();
  }
}

// ---------------- fused q+kv projection (even/odd interleave, 512 threads) ----------------
__global__ __launch_bounds__(512) void gemm_qkvproj(
    const u16* __restrict__ xbf, const int* __restrict__ qidx,
    const int* __restrict__ kvidx, const u16* __restrict__ wqbf,
    const u16* __restrict__ wkvbf, const float* __restrict__ kvscore,
    u16* __restrict__ qbuf, u16* __restrict__ kbuf, u16* __restrict__ vtbuf) {
  __shared__ __align__(16) u16 Asm[2][8192], Bsm[2][8192];
  __shared__ int ridx[128];
  int tid = threadIdx.x;
  int id = blockIdx.x;
  bool is_q = (id & 1) == 0;
  int sid = id >> 1;                 // 0..511 either way
  int bg = sid >> 5, r5 = sid & 31;
  int b = bg >> 2, g = bg & 3;
  int w = tid >> 6, lane = tid & 63;
  int col = lane & 15, quad = lane >> 4;
  int wr = w >> 2, wc = w & 3;

  if (is_q) {
    int col0 = (r5 & 3) * 128, row0 = (r5 >> 2) * 128;
    if (tid < 128) ridx[tid] = qidx[bg * NQS + row0 + tid];
    __syncthreads();
    Ptr2 P;
#pragma unroll
    for (int r = 0; r < 2; r++) {
      int G = r * 512 + tid;
      int row = G >> 3;
      int seg = (G & 7) ^ (row & 7);
      P.a[r] = xbf + ((size_t)b * SEQ + ridx[row]) * DM + seg * 8;
      P.b[r] = wqbf + ((size_t)g * DI + col0 + row) * DM + seg * 8;
    }
    f32x4 acc[4][2] = {};
    mfma_core512(P, Asm[0], Bsm[0], Asm[1], Bsm[1], DM / 64, tid, acc);
#pragma unroll
    for (int t = 0; t < 4; t++)
#pragma unroll
      for (int u = 0; u < 2; u++)
#pragma unroll
        for (int r = 0; r < 4; r++) {
          int rowg = row0 + wr * 64 + t * 16 + quad * 4 + r;
          int colg = col0 + wc * 32 + u * 16 + col;
          // pre-scale q by DH^-0.5 * log2(e) = 0.18033688: scores come out of
          // QK^T in log2 domain, so attn's exp is a bare v_exp_f32 (exp2).
          qbuf[((size_t)bg * NQS + rowg) * DI + colg] =
              f2bf(acc[t][u][r] * 0.18033688011112042f);
        }
  } else {
    int col0 = (r5 & 7) * 128, row0 = (r5 >> 3) * 128;
    if (tid < 128) ridx[tid] = kvidx[bg * NKS + row0 + tid];
    __syncthreads();
    Ptr2 P;
#pragma unroll
    for (int r = 0; r < 2; r++) {
      int G = r * 512 + tid;
      int row = G >> 3;
      int seg = (G & 7) ^ (row & 7);
      P.a[r] = xbf + ((size_t)b * SEQ + ridx[row]) * DM + seg * 8;
      P.b[r] = wkvbf + ((size_t)g * (2 * DI) + col0 + row) * DM + seg * 8;
    }
    f32x4 acc[4][2] = {};
    mfma_core512(P, Asm[0], Bsm[0], Asm[1], Bsm[1], DM / 64, tid, acc);
    if (col0 < DI) {
#pragma unroll
      for (int t = 0; t < 4; t++)
#pragma unroll
        for (int u = 0; u < 2; u++)
#pragma unroll
          for (int r = 0; r < 4; r++) {
            int rowg = row0 + wr * 64 + t * 16 + quad * 4 + r;
            int colg = col0 + wc * 32 + u * 16 + col;
            kbuf[((size_t)bg * NKS + rowg) * DI + colg] = f2bf(acc[t][u][r]);
          }
    } else {
#pragma unroll
      for (int t = 0; t < 4; t++) {
        int base = row0 + wr * 64 + t * 16 + quad * 4;  // base%4==0
        float sc0 = kvscore[bg * NKS + base + 0];
        float sc1 = kvscore[bg * NKS + base + 1];
        float sc2 = kvscore[bg * NKS + base + 2];
        float sc3 = kvscore[bg * NKS + base + 3];
#pragma unroll
        for (int u = 0; u < 2; u++) {
          int vc = col0 - DI + wc * 32 + u * 16 + col;  // 0..511
          int h = vc >> 6, d = vc & 63;
          u32 lo = (u32)f2bf(acc[t][u][0] * sc0) | ((u32)f2bf(acc[t][u][1] * sc1) << 16);
          u32 hi = (u32)f2bf(acc[t][u][2] * sc2) | ((u32)f2bf(acc[t][u][3] * sc3) << 16);
          // 4 consecutive n at one (h,d) row -> one aligned 8B store
          *(uint2*)&vtbuf[(((size_t)bg * NHD + h) * DHD + d) * VTS + base] =
              make_uint2(lo, hi);
        }
      }
    }
  }
}

// ---------------- out projection: bf16 oproj, 512 threads ----------------
__global__ __launch_bounds__(512) void gemm_outproj(
    const u16* __restrict__ obuf, const u16* __restrict__ woutbf,
    const float* __restrict__ qscore, u16* __restrict__ oproj_lo,
    u16* __restrict__ oproj_hi) {
  int bg = blockIdx.z, g = bg & 3;
  int row0 = blockIdx.y * 128, col0 = blockIdx.x * 128;
  __shared__ __align__(16) u16 Asm[2][8192], Bsm[2][8192];
  int tid = threadIdx.x;
  Ptr2 P;
#pragma unroll
  for (int r = 0; r < 2; r++) {
    int G = r * 512 + tid;
    int row = G >> 3;
    int seg = (G & 7) ^ (row & 7);
    P.a[r] = obuf + ((size_t)bg * NQS + row0 + row) * DI + seg * 8;
    P.b[r] = woutbf + ((size_t)g * DM + col0 + row) * DI + seg * 8;
  }
  f32x4 acc[4][2] = {};
  mfma_core512(P, Asm[0], Bsm[0], Asm[1], Bsm[1], DI / 64, tid, acc);
  int w = tid >> 6, lane = tid & 63;
  int col = lane & 15, quad = lane >> 4;
  int wr = w >> 2, wc = w & 3;
  u16* obase = (bg < 8 ? oproj_lo : oproj_hi) + (size_t)(bg & 7) * NQS * DM;
#pragma unroll
  for (int t = 0; t < 4; t++)
#pragma unroll
    for (int r = 0; r < 4; r++) {
      int rowg = row0 + wr * 64 + t * 16 + quad * 4 + r;
      float sc = qscore[bg * NQS + rowg];
      u16* orow = obase + (size_t)rowg * DM;
#pragma unroll
      for (int u = 0; u < 2; u++) {
        int colg = col0 + wc * 32 + u * 16 + col;
        orow[colg] = f2bfh(acc[t][u][r] * sc);
      }
    }
}

// ---------------- finalize: gather <=4 bf16 group rows, mean, null-token fill ----------------
__global__ __launch_bounds__(256) void finalize_gather(
    const u16* __restrict__ oproj_lo, const u16* __restrict__ oproj_hi,
    const int* __restrict__ qpos, const float* __restrict__ null_token,
    float* __restrict__ dout) {
  int blk = blockIdx.x;            // 0..16383 (4 b-values x 4096 tokens)
  int b = blk >> 12;
  int tok = blk & 4095;
  int tid = threadIdx.x;
  const u16* obase = (b < 2) ? oproj_lo : oproj_hi;
  int zoff = (b & 1) * 4;
  float4 acc = {0.f, 0.f, 0.f, 0.f};
  int cnt = 0;
#pragma unroll
  for (int g = 0; g < 4; g++) {
    int pos = qpos[(((b << 2) | g)) * 4096 + tok];  // block-uniform
    if (pos >= 0) {
      const uint2* row =
          (const uint2*)(obase + ((size_t)(zoff + g) * NQS + pos) * DM);
      uint2 v = row[tid];   // 4 bf16
      acc.x += bf2f((u16)(v.x & 0xFFFF));
      acc.y += bf2f((u16)(v.x >> 16));
      acc.z += bf2f((u16)(v.y & 0xFFFF));
      acc.w += bf2f((u16)(v.y >> 16));
      cnt++;
    }
  }
  float4* dst = (float4*)(dout + ((size_t)b * SEQ + tok) * DM) + tid;
  if (cnt > 0) {
    float inv = 1.0f / cnt;
    acc.x *= inv; acc.y *= inv; acc.z *= inv; acc.w *= inv;
    *dst = acc;
  } else {
    *dst = ((const float4*)null_token)[tid];
  }
}

// ---------------- MFMA flash attention v5: exp2-domain softmax + XCD-local grid ----------------
// Scores arrive in log2 domain (q pre-scaled by DH^-0.5*log2e), so every exp
// in the softmax is a bare v_exp_f32 (exp2f) with no log2e multiply. Tile max
// is a depth-4 tree (v_max3) instead of a 16-deep serial chain. Defer-max
// threshold 11.5 in log2 domain == e^8 bound (T13).
__global__ __launch_bounds__(256, 4) void attn_mfma(
    const u16* __restrict__ qbuf, const u16* __restrict__ kbuf,
    const u16* __restrict__ vtbuf, const float* __restrict__ null_kv,
    u16* __restrict__ obuf) {
  int id = blockIdx.x;
  int qt = id >> 7;           // 0..7
  int h = id & 7;             // XCD selector (i%8 == h)
  int bg = (id >> 3) & 15;    // 0..15
  int g = bg & 3;
  int tid = threadIdx.x;
  int w = tid >> 6, lane = tid & 63;
  int col = lane & 15, quad = lane >> 4;

  __shared__ __align__(16) u16 Ks[64][72];
  __shared__ __align__(16) u16 Vts[64][72];
  __shared__ __align__(16) u16 Ps[4][32][72];

  int q0 = qt * 128 + w * 32;
  const u16* qp0 = qbuf + ((size_t)bg * NQS + q0 + col) * DI + h * DHD + quad * 8;
  bf16x8 qa[2][2];
  qa[0][0] = *(const bf16x8*)qp0;
  qa[0][1] = *(const bf16x8*)(qp0 + 32);
  qa[1][0] = *(const bf16x8*)(qp0 + 16 * DI);
  qa[1][1] = *(const bf16x8*)(qp0 + 16 * DI + 32);

  // --- null-column prologue: exact online-softmax init (log2 domain) ---
  const float* kn = null_kv + ((size_t)(0 * NG + g) * NHD + h) * DHD;
  const float* vn = null_kv + ((size_t)(1 * NG + g) * NHD + h) * DHD;
  float m_run[2], l_lane[2];
  f32x4 oacc[2][4];
#pragma unroll
  for (int s = 0; s < 2; s++) {
    float sn = 0.f;
#pragma unroll
    for (int i = 0; i < 8; i++) {
      sn += (float)qa[s][0][i] * kn[quad * 8 + i];
      sn += (float)qa[s][1][i] * kn[32 + quad * 8 + i];
    }
    sn += __shfl_xor(sn, 16);
    sn += __shfl_xor(sn, 32);
    m_run[s] = sn;                       // running max = s'_null, p_null = 2^0 = 1
    l_lane[s] = (quad == 0) ? 1.f : 0.f; // null's contribution, seeded once
  }
#pragma unroll
  for (int t = 0; t < 4; t++) {
    float v = vn[t * 16 + col];          // oacc0 = 1 * v_null (all q rows)
    f32x4 tmp = {v, v, v, v};
    oacc[0][t] = tmp;
    oacc[1][t] = tmp;
  }

  // --- staging: 64x64 K tile + 64x64 V^T tile, 32B per thread each ---
  int sr = tid >> 2, ss = tid & 3;
  const u16* kptr = kbuf + ((size_t)bg * NKS + sr) * DI + h * DHD + ss * 16;
  const u16* vptr = vtbuf + (((size_t)bg * NHD + h) * DHD + sr) * VTS + ss * 16;
  uint4* kdst = (uint4*)&Ks[sr][ss * 16];
  uint4* vdst = (uint4*)&Vts[sr][ss * 16];
  uint4 ck0, ck1, cv0, cv1;
  { const uint4* p = (const uint4*)kptr; ck0 = p[0]; ck1 = p[1]; }
  { const uint4* p = (const uint4*)vptr; cv0 = p[0]; cv1 = p[1]; }

  for (int c = 0; c < 8; ++c) {
    // write-late: regs (loaded last iteration) -> LDS; then issue-early next
    kdst[0] = ck0; kdst[1] = ck1;
    vdst[0] = cv0; vdst[1] = cv1;
    if (c < 7) {
      const uint4* p = (const uint4*)(kptr + (size_t)(c + 1) * 64 * DI);
      ck0 = p[0]; ck1 = p[1];
      const uint4* q4 = (const uint4*)(vptr + (c + 1) * 64);
      cv0 = q4[0]; cv1 = q4[1];
    }
    __syncthreads();

    // QK^T swapped: sv[s][t] rows = k (quad*4+r within 16-tile t), col = q
    f32x4 sv[2][4];
#pragma unroll
    for (int t = 0; t < 4; t++) {
      bf16x8 kb0 = *(const bf16x8*)&Ks[t * 16 + col][quad * 8];
      bf16x8 kb1 = *(const bf16x8*)&Ks[t * 16 + col][quad * 8 + 32];
      f32x4 z = {0.f, 0.f, 0.f, 0.f};
      f32x4 s0 = __builtin_amdgcn_mfma_f32_16x16x32_bf16(kb0, qa[0][0], z, 0, 0, 0);
      sv[0][t] = __builtin_amdgcn_mfma_f32_16x16x32_bf16(kb1, qa[0][1], s0, 0, 0, 0);
      f32x4 s1 = __builtin_amdgcn_mfma_f32_16x16x32_bf16(kb0, qa[1][0], z, 0, 0, 0);
      sv[1][t] = __builtin_amdgcn_mfma_f32_16x16x32_bf16(kb1, qa[1][1], s1, 0, 0, 0);
    }

    // softmax per q-subtile (per-lane: one q = col, 16 k-values in-register)
#pragma unroll
    for (int s = 0; s < 2; s++) {
      // depth-4 max tree (v_max3-friendly), not a 16-deep serial chain
      float tm[4];
#pragma unroll
      for (int t = 0; t < 4; t++)
        tm[t] = fmaxf(fmaxf(sv[s][t][0], sv[s][t][1]),
                      fmaxf(sv[s][t][2], sv[s][t][3]));
      float pm = fmaxf(fmaxf(tm[0], tm[1]), fmaxf(tm[2], tm[3]));
      pm = fmaxf(pm, __shfl_xor(pm, 16));
      pm = fmaxf(pm, __shfl_xor(pm, 32));
      if (!__all(pm <= m_run[s] + 11.5f)) {  // T13 defer-max (log2 domain, ~e^8)
        float mnew = fmaxf(m_run[s], pm);
        float alpha = exp2f(m_run[s] - mnew);
        m_run[s] = mnew;
        l_lane[s] *= alpha;
#pragma unroll
        for (int r = 0; r < 4; r++) {
          float a_o = __shfl(alpha, quad * 4 + r);
#pragma unroll
          for (int t = 0; t < 4; t++) oacc[s][t][r] *= a_o;
        }
      }
      float rs = 0.f;
#pragma unroll
      for (int t = 0; t < 4; t++) {
        float p0 = exp2f(sv[s][t][0] - m_run[s]);
        float p1 = exp2f(sv[s][t][1] - m_run[s]);
        float p2 = exp2f(sv[s][t][2] - m_run[s]);
        float p3 = exp2f(sv[s][t][3] - m_run[s]);
        rs += (p0 + p1) + (p2 + p3);
        u32 lo = (u32)f2bfh(p0) | ((u32)f2bfh(p1) << 16);
        u32 hi = (u32)f2bfh(p2) | ((u32)f2bfh(p3) << 16);
        // 4 consecutive k per lane -> one b64 store
        *(uint2*)&Ps[w][s * 16 + col][t * 16 + quad * 4] = make_uint2(lo, hi);
      }
      l_lane[s] += rs;
    }

    // PV: vb fragments reused for both q-subtiles
#pragma unroll
    for (int s2 = 0; s2 < 2; s2++) {
      bf16x8 pa0 = *(const bf16x8*)&Ps[w][col][s2 * 32 + quad * 8];
      bf16x8 pa1 = *(const bf16x8*)&Ps[w][16 + col][s2 * 32 + quad * 8];
#pragma unroll
      for (int t = 0; t < 4; t++) {
        bf16x8 vb = *(const bf16x8*)&Vts[t * 16 + col][s2 * 32 + quad * 8];
        oacc[0][t] = __builtin_amdgcn_mfma_f32_16x16x32_bf16(pa0, vb, oacc[0][t], 0, 0, 0);
        oacc[1][t] = __builtin_amdgcn_mfma_f32_16x16x32_bf16(pa1, vb, oacc[1][t], 0, 0, 0);
      }
    }
    __syncthreads();
  }

  // epilogue: reduce l across quads, redistribute to C layout, write
#pragma unroll
  for (int s = 0; s < 2; s++) {
    float l = l_lane[s];
    l += __shfl_xor(l, 16);
    l += __shfl_xor(l, 32);
    float inv = 1.0f / l;
#pragma unroll
    for (int r = 0; r < 4; r++) {
      float ir = __shfl(inv, quad * 4 + r);
#pragma unroll
      for (int t = 0; t < 4; t++) {
        obuf[((size_t)bg * NQS + q0 + s * 16 + quad * 4 + r) * DI + h * DHD +
             t * 16 + col] = f2bfh(oacc[s][t][r] * ir);
      }
    }
  }
}

extern "C" void kernel_launch(void* const* d_in, const int* in_sizes, int n_in,
                              void* d_out, int out_size, void* d_ws, size_t ws_size,
                              hipStream_t stream) {
  const float* x = (const float*)d_in[0];
  const float* wqr = (const float*)d_in[1];
  const float* wkvr = (const float*)d_in[2];
  const float* wq = (const float*)d_in[3];
  const float* wkv = (const float*)d_in[4];
  const float* wout = (const float*)d_in[5];
  const float* nullkv = (const float*)d_in[6];
  const float* nulltok = (const float*)d_in[7];
  float* out = (float*)d_out;
  char* ws = (char*)d_ws;
  // workspace layout (bytes)
  float* qlog = (float*)(ws + 0);                  // 256 KB
  float* kvlog = (float*)(ws + 262144);            // 256 KB
  int* qidx = (int*)(ws + 524288);                 // 64 KB
  int* kvidx = (int*)(ws + 589824);                // 32 KB
  float* qscore = (float*)(ws + 622592);           // 64 KB
  float* kvscore = (float*)(ws + 688128);          // 32 KB
  u16* qbuf = (u16*)(ws + 786432);                 // 16 MB  [16][1024][512]
  u16* kbuf = (u16*)(ws + 17563648);               // 8 MB   [16][512][512]
  u16* vtbuf = (u16*)(ws + 25952256);              // 8.13MB [16][8][64][520]
  u16* obuf = (u16*)(ws + 34476032);               // 16 MB  [16][1024][512]
  u16* xbf = (u16*)(ws + 51253248);                // 32 MB  [4][4096][1024]
  u16* wqbf = (u16*)(ws + 84807680);               // 4 MB   [4][512][1024]
  u16* wkvbf = (u16*)(ws + 89001984);              // 8 MB   [4][1024][1024]
  u16* woutbf = (u16*)(ws + 97390592);             // 4 MB   [4][1024][512]
  // dead-region reuse (stream-ordered):
  //  - qpos (256 KB) in qlog's region, written directly by topk
  //  - oproj_lo (16 MB bf16, bg 0..7)  in qbuf region (dead after attn)
  //  - oproj_hi (16 MB bf16, bg 8..15) in xbf region (dead after qkvproj)
  int* qpos = (int*)(ws + 0);
  u16* oproj_lo = (u16*)(ws + 786432);
  u16* oproj_hi = (u16*)(ws + 51253248);

  router_kernel<<<2048, 256, 0, stream>>>(x, wqr, wkvr, qlog, kvlog, xbf);
  topk_kernel<<<2080, 256, 0, stream>>>(qlog, kvlog, qidx, qscore, kvidx,
                                        kvscore, qpos, wq, wkv, wout, wqbf,
                                        wkvbf, woutbf);
  gemm_qkvproj<<<1024, 512, 0, stream>>>(xbf, qidx, kvidx, wqbf, wkvbf, kvscore,
                                         qbuf, kbuf, vtbuf);
  attn_mfma<<<1024, 256, 0, stream>>>(qbuf, kbuf, vtbuf, nullkv, obuf);
  gemm_outproj<<<dim3(8, 8, 16), 512, 0, stream>>>(obuf, woutbf, qscore,
                                                   oproj_lo, oproj_hi);
  finalize_gather<<<16384, 256, 0, stream>>>(oproj_lo, oproj_hi, qpos, nulltok,
                                             out);
}